// Round 10
// baseline (160.960 us; speedup 1.0000x reference)
//
#include <hip/hip_runtime.h>
#include <hip/hip_bf16.h>

// AttentionConv2d: B=8, C_IN=256, H=W=32 (HW=1024), DK=DV=256, NH=8, DKH=DVH=32,
// C_OUT=512, 3x3 conv pad=1. fp32 storage in/out; bf16 intermediates + MFMA.
//
// Workspace (bf16 elements, EXACTLY 16 MB):
//   xT    [8 b][1024 l][256 ci]  @ 0          read by fused conv3+qkv
//   attL  [8 b][1024 l][256 ch]  @ 0          alias of xT (attn writes after fused done)
//   qT    [64 head][1024][32]    @ 2,097,152
//   kR    [64 head][1024][32]    @ 4,194,304
//   vF    [64 head][16 c][4 q][64 lane][8]  @ 6,291,456   (PV-fragment order)
// prep -> convqkv(fused) -> attn -> attnout.
// R21 (MEASUREMENT ROUND): attn = R19 exactly, but grid 2048 with rep-bit
// (bid>>10); both reps compute/write byte-identical attL (benign same-value
// writes). Purpose: the attn dispatch doubles to ~2x its true duration,
// crossing the ~43us fill floor so rocprof's top-5 finally shows attn's
// counters (MfmaUtil/VALUBusy/Occupancy/FETCH/bank-conflicts) for diagnosis.
// Total will regress by ~attn-duration this round by design; best-known
// remains R19's 138.5 and will be restored next round with the counter-guided
// optimization.

typedef __hip_bfloat16 bf16;
typedef __attribute__((ext_vector_type(8))) short bf16x8;
typedef __attribute__((ext_vector_type(4))) float f32x4;

__device__ __forceinline__ float blo(unsigned int v) { return __uint_as_float(v << 16); }
__device__ __forceinline__ float bhi(unsigned int v) { return __uint_as_float(v & 0xffff0000u); }
__device__ __forceinline__ unsigned short f2bfbits(float f) {
  union { bf16 h; unsigned short u; } cv; cv.h = __float2bfloat16(f); return cv.u;
}
// v_cvt_pk_bf16_f32: dst.lo = bf16(lo), dst.hi = bf16(hi). RNE, 1 VALU op.
__device__ __forceinline__ unsigned int cvt_pk_bf16(float lo, float hi) {
  unsigned int r;
  asm("v_cvt_pk_bf16_f32 %0, %1, %2" : "=v"(r) : "v"(lo), "v"(hi));
  return r;
}
__device__ __forceinline__ float exp2_f(float x) {
#if __has_builtin(__builtin_amdgcn_exp2f)
  return __builtin_amdgcn_exp2f(x);
#else
  return exp2f(x);
#endif
}

// ---------------------------------------------------------------------------
// K0: prep — xT transpose to bf16 + w_out bf16 chunk-blocked into wob0/wob1.
// blocks 0..2047: xT; 2048..2083: w_out. grid 2084.
// ---------------------------------------------------------------------------
__global__ __launch_bounds__(256) void prep_kernel(
    const float* __restrict__ x, const float* __restrict__ wout,
    bf16* __restrict__ xT, bf16* __restrict__ wob0, bf16* __restrict__ wob1)
{
  int bid = blockIdx.x, tid = threadIdx.x;
  if (bid < 2048) {
    __shared__ float t[32 * 33];
    int b = bid >> 8, rem = bid & 255;
    int ci0 = (rem >> 5) * 32, l0 = (rem & 31) * 32;
    {
      int ciL = tid >> 3, lL4 = (tid & 7) * 4;
      float4 v = *(const float4*)(x + (size_t)(b * 256 + ci0 + ciL) * 1024 + l0 + lL4);
      t[ciL * 33 + lL4 + 0] = v.x; t[ciL * 33 + lL4 + 1] = v.y;
      t[ciL * 33 + lL4 + 2] = v.z; t[ciL * 33 + lL4 + 3] = v.w;
    }
    __syncthreads();
    {
      int lL = tid >> 3, cS = (tid & 7) * 4;
      unsigned int p0 = (unsigned int)f2bfbits(t[(cS + 0) * 33 + lL]) |
                        ((unsigned int)f2bfbits(t[(cS + 1) * 33 + lL]) << 16);
      unsigned int p1 = (unsigned int)f2bfbits(t[(cS + 2) * 33 + lL]) |
                        ((unsigned int)f2bfbits(t[(cS + 3) * 33 + lL]) << 16);
      uint2 u2; u2.x = p0; u2.y = p1;
      *(uint2*)(xT + ((size_t)(b * 1024) + l0 + lL) * 256 + ci0 + cS) = u2;
    }
  } else {
    int t0 = (bid - 2048) * 256 + tid;       // 0..9215
#pragma unroll
    for (int s = 0; s < 8; ++s) {
      int u = s * 9216 + t0;                 // dst uint4 index 0..73727
      int chunkblk = u / 2304;
      int within = u - chunkblk * 2304;
      int co63 = within / 36;
      int r = within - co63 * 36;            // kidx*4 + cig
      int kidx = r >> 2, cig = r & 3;
      int co = (chunkblk >> 3) * 64 + co63;
      int ci = (chunkblk & 7) * 32 + cig * 8;
      union { unsigned short h[8]; uint4 u4; } pk;
#pragma unroll
      for (int j = 0; j < 8; ++j)
        pk.h[j] = f2bfbits(wout[(size_t)(co * 256 + ci + j) * 9 + kidx]);
      bf16* dst = (chunkblk < 28) ? (wob0 + (size_t)chunkblk * 18432)
                                  : (wob1 + (size_t)(chunkblk - 28) * 18432);
      *(uint4*)(dst + (size_t)within * 8) = pk.u4;
    }
  }
}

// ---------------------------------------------------------------------------
// K1 (fused): blocks 0..255 = conv3 (3x3, MFMA shift-GEMM, prepacked weights);
// 256..1023 = qkv GEMM. Both only read xT -> co-resident, mutual latency hiding.
// V epilogue writes fragment-ordered vF (R17).
// ---------------------------------------------------------------------------
__global__ __launch_bounds__(256) void convqkv_kernel(
    const bf16* __restrict__ xT,
    const bf16* __restrict__ wob0, const bf16* __restrict__ wob1,
    const float* __restrict__ b_out, float* __restrict__ out,
    const float* __restrict__ wq, const float* __restrict__ b_qkv,
    bf16* __restrict__ qT, bf16* __restrict__ kR, bf16* __restrict__ vW)
{
  __shared__ __align__(16) short smem[27104];
  int tid = threadIdx.x, lane = tid & 63, wave = tid >> 6;
  int m16 = lane & 15, quad = lane >> 4;

  if (blockIdx.x < 256) {
    short* wS = smem;            // [64 co][296]
    short* xS = smem + 18944;    // [6 rows][34 cols][40]
    int bid = blockIdx.x;
    int rc = bid & 7, cotile = (bid >> 3) & 3, b = bid >> 5;
    int y0 = rc * 4;

    f32x4 acc[8];
#pragma unroll
    for (int t = 0; t < 8; ++t) acc[t] = (f32x4){0.f, 0.f, 0.f, 0.f};

    for (int ck = 0; ck < 8; ++ck) {
      __syncthreads();
      int cb = cotile * 8 + ck;
      const bf16* wbase = (cb < 28) ? (wob0 + (size_t)cb * 18432)
                                    : (wob1 + (size_t)(cb - 28) * 18432);
#pragma unroll
      for (int r = 0; r < 9; ++r) {
        int u = r * 256 + tid;
        *(uint4*)(wS + (u / 36) * 296 + (u % 36) * 8) = *(const uint4*)(wbase + (size_t)u * 8);
      }
#pragma unroll
      for (int r = 0; r < 3; ++r) {
        int u = r * 256 + tid;
        int pos = u >> 2, seg = u & 3;
        int row = pos >> 5, col = pos & 31;
        int gy = y0 - 1 + row;
        uint4 val = make_uint4(0u, 0u, 0u, 0u);
        if (gy >= 0 && gy < 32)
          val = *(const uint4*)(xT + ((size_t)(b * 1024) + gy * 32 + col) * 256 + ck * 32 + seg * 8);
        *(uint4*)(xS + (row * 34 + col + 1) * 40 + seg * 8) = val;
      }
      if (tid < 48) {
        int pos = tid >> 2, seg = tid & 3;
        int row = pos >> 1, side = pos & 1;
        *(uint4*)(xS + (row * 34 + side * 33) * 40 + seg * 8) = make_uint4(0u, 0u, 0u, 0u);
      }
      __syncthreads();
#pragma unroll
      for (int kidx = 0; kidx < 9; ++kidx) {
        int dy = kidx / 3, dx = kidx - dy * 3;
        bf16x8 af = *(const bf16x8*)(wS + (wave * 16 + m16) * 296 + kidx * 32 + quad * 8);
#pragma unroll
        for (int t = 0; t < 8; ++t) {
          int row = (t >> 1) + dy;
          int col = (t & 1) * 16 + m16 + dx;
          bf16x8 bf = *(const bf16x8*)(xS + (row * 34 + col) * 40 + quad * 8);
          acc[t] = __builtin_amdgcn_mfma_f32_16x16x32_bf16(af, bf, acc[t], 0, 0, 0);
        }
      }
    }

    int cob = cotile * 64 + wave * 16 + quad * 4;
#pragma unroll
    for (int i = 0; i < 4; ++i) {
      float bv = b_out[cob + i];
#pragma unroll
      for (int t = 0; t < 8; ++t) {
        int y = y0 + (t >> 1), xc = (t & 1) * 16 + m16;
        out[((size_t)(b * 512) + cob + i) * 1024 + y * 32 + xc] = acc[t][i] + bv;
      }
    }
  } else {
    short* aS = smem;            // [64][72]
    short* bS = smem + 4608;     // [128][72]
    int bid2 = blockIdx.x - 256;
    int ltile = bid2 & 7;
    int rest = bid2 >> 3;
    int ctile = rest % 12;
    int b = rest / 12;
    int l0 = ltile * 128;
    int cbase = ctile * 64;

    f32x4 acc[8];
#pragma unroll
    for (int t = 0; t < 8; ++t) acc[t] = (f32x4){0.f, 0.f, 0.f, 0.f};

    for (int ck = 0; ck < 4; ++ck) {
      __syncthreads();
#pragma unroll
      for (int r = 0; r < 4; ++r) {
        int u = r * 256 + tid;
        int c = u >> 4, s4 = u & 15;
        float4 v = *(const float4*)(wq + (size_t)(cbase + c) * 256 + ck * 64 + s4 * 4);
        unsigned int p0 = (unsigned int)f2bfbits(v.x) | ((unsigned int)f2bfbits(v.y) << 16);
        unsigned int p1 = (unsigned int)f2bfbits(v.z) | ((unsigned int)f2bfbits(v.w) << 16);
        uint2 u2; u2.x = p0; u2.y = p1;
        *(uint2*)(aS + c * 72 + s4 * 4) = u2;
      }
#pragma unroll
      for (int r = 0; r < 4; ++r) {
        int u = r * 256 + tid;
        int l = u >> 3, seg = u & 7;
        *(uint4*)(bS + l * 72 + seg * 8) =
            *(const uint4*)(xT + ((size_t)(b * 1024) + l0 + l) * 256 + ck * 64 + seg * 8);
      }
      __syncthreads();
#pragma unroll
      for (int ks = 0; ks < 2; ++ks) {
        bf16x8 af = *(const bf16x8*)(aS + (wave * 16 + m16) * 72 + ks * 32 + quad * 8);
#pragma unroll
        for (int t = 0; t < 8; ++t) {
          bf16x8 bf = *(const bf16x8*)(bS + (t * 16 + m16) * 72 + ks * 32 + quad * 8);
          acc[t] = __builtin_amdgcn_mfma_f32_16x16x32_bf16(af, bf, acc[t], 0, 0, 0);
        }
      }
    }

    __syncthreads();
    short* ldsT = smem + wave * 3072;
    int cb = cbase + wave * 16;
    bool isq = (ctile < 4);
    float bv[4];
#pragma unroll
    for (int i = 0; i < 4; ++i) bv[i] = b_qkv[cb + quad * 4 + i];
#pragma unroll
    for (int t = 0; t < 8; ++t) {
#pragma unroll
      for (int i = 0; i < 4; ++i) {
        float v = acc[t][i] + bv[i];
        if (isq) v *= 0.17677669529663689f;  // 32^-0.5, pre-rel-logits
        ldsT[(t * 16 + m16) * 24 + quad * 4 + i] = (short)f2bfbits(v);
      }
    }
    if (ctile < 8) {
      bf16* dst = isq ? qT : kR;
      int coff = isq ? cb : cb - 256;
#pragma unroll
      for (int rep = 0; rep < 4; ++rep) {
        int u = rep * 64 + lane;
        int l = u >> 1, half = u & 1;
        int c0 = coff + half * 8;
        int head = b * 8 + (c0 >> 5), d0 = c0 & 31;
        *(uint4*)(dst + ((size_t)head * 1024 + l0 + l) * 32 + d0) =
            *(const uint4*)(ldsT + l * 24 + half * 8);
      }
    } else {
      // fragment-ordered vF writes (R17).
      int dcol = lane >> 2, lg = lane & 3;
      int c2 = (cb - 512) + dcol;
      int head = b * 8 + (c2 >> 5), gd = c2 & 31;
      int dt = gd >> 4, m16v = gd & 15;
      int cch = ltile * 2 + (lg >> 1);
      int ksv = lg & 1;
      bf16* vbase = vW + (size_t)head * 32768 + cch * 2048 + (dt * 2 + ksv) * 512 + m16v * 8;
#pragma unroll
      for (int s = 0; s < 4; ++s) {
#pragma unroll
        for (int p = 0; p < 4; ++p) {
          int j0 = lg * 32 + s * 8 + p * 2;
          unsigned int u0 = (unsigned short)ldsT[j0 * 24 + dcol];
          unsigned int u1 = (unsigned short)ldsT[(j0 + 1) * 24 + dcol];
          unsigned int w = u0 | (u1 << 16);
          int quadp = (s & 1) * 2 + (p >> 1);
          int jj = (p & 1) * 2 + (s >> 1) * 4;
          *(unsigned int*)(vbase + quadp * 128 + jj) = w;
        }
      }
    }
  }
}

// ---------------------------------------------------------------------------
// K3: MFMA attention, R21 = R19 with grid 2048 (rep-doubled for measurement).
// rep = bid>>10 (both reps compute identical results; same-value attL writes
// are benign). inner = bid&1023 drives the R19 mapping. 2-wave blocks, each
// wave owns 32 q rows (2 subtiles sharing every K/V fetch); MFMA rel-logit
// tables (one barrier); K-loop zero barriers, direct global K (kR) + V (vF
// fragment-order) reads, rolled loop.
// LDS: RWf f32 [64][68] @0 (17408 B); RHf @17408. Total 34816 B.
// ---------------------------------------------------------------------------
__global__ __launch_bounds__(128) void attn_mfma_kernel(
    const bf16* __restrict__ qT, const bf16* __restrict__ kR, const bf16* __restrict__ vW,
    const float* __restrict__ krw, const float* __restrict__ krh,
    bf16* __restrict__ attL)
{
  __shared__ __align__(16) char smem[34816];
  float* RWf = (float*)smem;             // [64 m][68]
  float* RHf = (float*)(smem + 17408);   // [64 m][68]

  const float L2E = 1.4426950408889634f;

  int tid = threadIdx.x;
  int lane = tid & 63, wave = tid >> 6;      // wave in {0,1}
  int m16 = lane & 15, quad = lane >> 4;
  int bid = blockIdx.x & 1023;               // rep bit (bid>>10) intentionally unused
  // same head -> same blockIdx mod 8 -> same XCD (round-robin heuristic;
  // (1024+i)%8 == i%8 so both reps of a head stay on its XCD)
  int head = ((bid & 7) << 3) | ((bid >> 3) & 7);
  int qt = bid >> 6;                 // 0..15, 64 q rows per block
  int row0 = qt * 64;
  int b = head >> 3, h = head & 7;

  // ---- rel-logit tables via MFMA (wave w: m-tiles 2w, 2w+1) ----
#pragma unroll
  for (int mt = 0; mt < 2; ++mt) {
    int mtile = wave * 2 + mt;
    int mrow = mtile * 16 + m16;
    bool valid = (mrow < 63);
    float4 w0 = make_float4(0.f, 0.f, 0.f, 0.f), w1 = w0, h0 = w0, h1 = w0;
    if (valid) {
      w0 = *(const float4*)(krw + mrow * 32 + quad * 8);
      w1 = *(const float4*)(krw + mrow * 32 + quad * 8 + 4);
      h0 = *(const float4*)(krh + mrow * 32 + quad * 8);
      h1 = *(const float4*)(krh + mrow * 32 + quad * 8 + 4);
    }
    union { unsigned int w[4]; bf16x8 v; } aw, ah;
    aw.w[0] = cvt_pk_bf16(w0.x * L2E, w0.y * L2E);
    aw.w[1] = cvt_pk_bf16(w0.z * L2E, w0.w * L2E);
    aw.w[2] = cvt_pk_bf16(w1.x * L2E, w1.y * L2E);
    aw.w[3] = cvt_pk_bf16(w1.z * L2E, w1.w * L2E);
    ah.w[0] = cvt_pk_bf16(h0.x * L2E, h0.y * L2E);
    ah.w[1] = cvt_pk_bf16(h0.z * L2E, h0.w * L2E);
    ah.w[2] = cvt_pk_bf16(h1.x * L2E, h1.y * L2E);
    ah.w[3] = cvt_pk_bf16(h1.z * L2E, h1.w * L2E);
#pragma unroll
    for (int nt = 0; nt < 4; ++nt) {
      bf16x8 qf = *(const bf16x8*)(
          qT + ((size_t)head * 1024 + row0 + nt * 16 + m16) * 32 + quad * 8);
      f32x4 z = (f32x4){0.f, 0.f, 0.f, 0.f};
      f32x4 dw = __builtin_amdgcn_mfma_f32_16x16x32_bf16(aw.v, qf, z, 0, 0, 0);
      f32x4 dh = __builtin_amdgcn_mfma_f32_16x16x32_bf16(ah.v, qf, z, 0, 0, 0);
#pragma unroll
      for (int i = 0; i < 4; ++i) {
        int mr = mtile * 16 + quad * 4 + i;     // D row = m (rel index)
        RWf[mr * 68 + nt * 16 + m16] = dw[i];
        RHf[mr * 68 + nt * 16 + m16] = dh[i];
      }
    }
  }
  __syncthreads();   // tables complete; read-only from here; NO more barriers

  // ---- Q fragments (B-operand) + chunk-invariant RW registers, per subtile
  bf16x8 afrag[2];
  float rwreg[2][2][4];
  int qloc0 = wave * 32 + m16;       // sub 0; sub 1 adds 16
#pragma unroll
  for (int sub = 0; sub < 2; ++sub) {
    int qloc = qloc0 + sub * 16;
    afrag[sub] = *(const bf16x8*)(
        qT + ((size_t)head * 1024 + row0 + qloc) * 32 + quad * 8);
    int qm = qloc & 31;
#pragma unroll
    for (int par = 0; par < 2; ++par)
#pragma unroll
      for (int i = 0; i < 4; ++i)
        rwreg[sub][par][i] = RWf[(par * 16 + quad * 4 + i - qm + 31) * 68 + qloc];
  }
  int qy = qt * 2 + wave;            // (qloc>>5) == wave for both subtiles
  const float* rhp0 = RHf + (31 - qy) * 68 + qloc0;        // +c*2*68 per chunk
  const float* rhp1 = rhp0 + 16;                           // sub 1 column

  // per-lane global fragment pointers (wave-independent: subs share fetches)
  const bf16* kp = kR + (size_t)head * 32768 + m16 * 32 + quad * 8;   // +c*2048 +t*512
  const bf16* vp = vW + (size_t)head * 32768 + lane * 8;              // +c*2048 +(dt*2+ks)*512

  f32x4 oacc[2][2];
#pragma unroll
  for (int sub = 0; sub < 2; ++sub) {
    oacc[sub][0] = (f32x4){0.f, 0.f, 0.f, 0.f};
    oacc[sub][1] = (f32x4){0.f, 0.f, 0.f, 0.f};
  }
  float rsp[2] = {0.f, 0.f};

#pragma unroll 1
  for (int c = 0; c < 16; ++c) {
    // issue all 8 shared fragment loads up front (latency overlaps exp below)
    union { uint4 u; bf16x8 v; } kf[4], vf[4];
#pragma unroll
    for (int t = 0; t < 4; ++t)
      kf[t].u = *(const uint4*)(kp + c * 2048 + t * 512);
#pragma unroll
    for (int q = 0; q < 4; ++q)         // q = dt*2 + ks
      vf[q].u = *(const uint4*)(vp + c * 2048 + q * 512);

    // RH for this chunk (per sub column; rows uniform per wave)
    float rh[2][2];
    rh[0][0] = rhp0[(c * 2 + 0) * 68];  rh[0][1] = rhp0[(c * 2 + 1) * 68];
    rh[1][0] = rhp1[(c * 2 + 0) * 68];  rh[1][1] = rhp1[(c * 2 + 1) * 68];

    // QK^T swapped: A = K frag (rows=keys), B = Qfrag[sub] (cols=q)
    f32x4 sacc[2][4];
#pragma unroll
    for (int t = 0; t < 4; ++t) {
      f32x4 z = (f32x4){0.f, 0.f, 0.f, 0.f};
#pragma unroll
      for (int sub = 0; sub < 2; ++sub)
        sacc[sub][t] = __builtin_amdgcn_mfma_f32_16x16x32_bf16(kf[t].v, afrag[sub], z, 0, 0, 0);
    }

    // softmax numerators in-register (lane q = qloc, key = t*16+quad*4+i)
    unsigned int pk[2][4][2];
#pragma unroll
    for (int sub = 0; sub < 2; ++sub) {
#pragma unroll
      for (int t = 0; t < 4; ++t) {
        float rhv = rh[sub][t >> 1];
        float e0 = exp2_f(fmaf(sacc[sub][t][0], L2E, rwreg[sub][t & 1][0] + rhv));
        float e1 = exp2_f(fmaf(sacc[sub][t][1], L2E, rwreg[sub][t & 1][1] + rhv));
        float e2 = exp2_f(fmaf(sacc[sub][t][2], L2E, rwreg[sub][t & 1][2] + rhv));
        float e3 = exp2_f(fmaf(sacc[sub][t][3], L2E, rwreg[sub][t & 1][3] + rhv));
        rsp[sub] += (e0 + e1) + (e2 + e3);
        pk[sub][t][0] = cvt_pk_bf16(e0, e1);
        pk[sub][t][1] = cvt_pk_bf16(e2, e3);
      }
    }

    // PV: O^T = mfma(Vfrag, P^T). kappa = ks*32 + (j>>2)*16 + quad*4 + (j&3).
#pragma unroll
    for (int ks = 0; ks < 2; ++ks) {
#pragma unroll
      for (int sub = 0; sub < 2; ++sub) {
        union { unsigned int w[4]; bf16x8 v; } pf;
        pf.w[0] = pk[sub][2 * ks][0];     pf.w[1] = pk[sub][2 * ks][1];
        pf.w[2] = pk[sub][2 * ks + 1][0]; pf.w[3] = pk[sub][2 * ks + 1][1];
#pragma unroll
        for (int dt = 0; dt < 2; ++dt) {
          oacc[sub][dt] = __builtin_amdgcn_mfma_f32_16x16x32_bf16(
              vf[dt * 2 + ks].v, pf.v, oacc[sub][dt], 0, 0, 0);
        }
      }
    }
  }

  // ---- epilogue: reduce row-sums across quads, normalize, store ----
#pragma unroll
  for (int sub = 0; sub < 2; ++sub) {
    rsp[sub] += __shfl_xor(rsp[sub], 16, 64);
    rsp[sub] += __shfl_xor(rsp[sub], 32, 64);
    float invs = 1.0f / rsp[sub];
    int grow = row0 + qloc0 + sub * 16;
#pragma unroll
    for (int dt = 0; dt < 2; ++dt) {
      uint2 st;
      st.x = cvt_pk_bf16(oacc[sub][dt][0] * invs, oacc[sub][dt][1] * invs);
      st.y = cvt_pk_bf16(oacc[sub][dt][2] * invs, oacc[sub][dt][3] * invs);
      *(uint2*)(attL + ((size_t)b * 1024 + grow) * 256 + h * 32 + dt * 16 + quad * 4) = st;
    }
  }
}

// ---------------------------------------------------------------------------
// K4: attnout 1x1 conv as MFMA GEMM 256 x 1024 x 256 per batch. (R6 version)
// Runs last; overwrites the d_out ch256+ regions that hosted wo_bf.
// ---------------------------------------------------------------------------
__global__ __launch_bounds__(256) void attnout_mfma_kernel(
    const bf16* __restrict__ attL, const float* __restrict__ w, const float* __restrict__ bias,
    float* __restrict__ out)
{
  __shared__ __align__(16) short smem[13824];
  short* aS = smem;            // [64 co][72]
  short* bS = smem + 4608;     // [128 l][72]

  int tid = threadIdx.x, lane = tid & 63, wave = tid >> 6;
  int m16 = lane & 15, quad = lane >> 4;
  int l0 = blockIdx.x * 128;
  int cotile = blockIdx.y;
  int b = blockIdx.z;
  int cbase = cotile * 64;

  f32x4 acc[8];
#pragma unroll
  for (int t = 0; t < 8; ++t) acc[t] = (f32x4){0.f, 0.f, 0.f, 0.f};

  for (int ck = 0; ck < 4; ++ck) {
    __syncthreads();
#pragma unroll
    for (int r = 0; r < 4; ++r) {
      int u = r * 256 + tid;
      int c = u >> 4, s4 = u & 15;
      float4 v = *(const float4*)(w + (size_t)(cbase + c) * 256 + ck * 64 + s4 * 4);
      unsigned int p0 = (unsigned int)f2bfbits(v.x) | ((unsigned int)f2bfbits(v.y) << 16);
      unsigned int p1 = (unsigned int)f2bfbits(v.z) | ((unsigned int)f2bfbits(v.w) << 16);
      uint2 u2; u2.x = p0; u2.y = p1;
      *(uint2*)(aS + c * 72 + s4 * 4) = u2;
    }
#pragma unroll
    for (int r = 0; r < 4; ++r) {
      int u = r * 256 + tid;
      int l = u >> 3, seg = u & 7;
      *(uint4*)(bS + l * 72 + seg * 8) =
          *(const uint4*)(attL + ((size_t)(b * 1024) + l0 + l) * 256 + ck * 64 + seg * 8);
    }
    __syncthreads();
#pragma unroll
    for (int ks = 0; ks < 2; ++ks) {
      bf16x8 af = *(const bf16x8*)(aS + (wave * 16 + m16) * 72 + ks * 32 + quad * 8);
#pragma unroll
      for (int t = 0; t < 8; ++t) {
        bf16x8 bf = *(const bf16x8*)(bS + (t * 16 + m16) * 72 + ks * 32 + quad * 8);
        acc[t] = __builtin_amdgcn_mfma_f32_16x16x32_bf16(af, bf, acc[t], 0, 0, 0);
      }
    }
  }

  int co = cbase + wave * 16 + quad * 4;
#pragma unroll
  for (int i = 0; i < 4; ++i) {
    float bv = bias[co + i];
    size_t obase = ((size_t)(b * 512) + 256 + co + i) * 1024 + l0;
#pragma unroll
    for (int t = 0; t < 8; ++t)
      out[obase + t * 16 + m16] = acc[t][i] + bv;
  }
}

// ---------------------------------------------------------------------------
extern "C" void kernel_launch(void* const* d_in, const int* in_sizes, int n_in,
                              void* d_out, int out_size, void* d_ws, size_t ws_size,
                              hipStream_t stream) {
  const float* x      = (const float*)d_in[0];
  const float* w_qkv  = (const float*)d_in[1];
  const float* b_qkv  = (const float*)d_in[2];
  const float* w_attn = (const float*)d_in[3];
  const float* b_attn = (const float*)d_in[4];
  const float* w_out  = (const float*)d_in[5];
  const float* b_out  = (const float*)d_in[6];
  const float* krw    = (const float*)d_in[7];
  const float* krh    = (const float*)d_in[8];
  float* out = (float*)d_out;

  bf16* ws    = (bf16*)d_ws;
  bf16* xT    = ws;                 // [0, 2,097,152)  read by fused conv3+qkv
  bf16* attL  = ws;                 // alias of xT     (attn -> attnout, after fused)
  bf16* qT    = ws + 2097152;       // [2,097,152, 4,194,304)
  bf16* kR    = ws + 4194304;       // [4,194,304, 6,291,456)
  bf16* vF    = ws + 6291456;       // [6,291,456, 8,388,608)  fragment-ordered V

  // wo_bf in d_out's attention half (dead until attnout overwrites it)
  bf16* wob0 = (bf16*)(out + (size_t)(0 * 512 + 256) * 1024);
  bf16* wob1 = (bf16*)(out + (size_t)(1 * 512 + 256) * 1024);

  prep_kernel<<<dim3(2084), 256, 0, stream>>>(x, w_out, xT, wob0, wob1);
  convqkv_kernel<<<dim3(1024), 256, 0, stream>>>(xT, wob0, wob1, b_out, out,
                                                 w_qkv, b_qkv, qT, kR, vF);
  // R21 measurement: grid 2048 = 2 reps of the 1024-block R19 dispatch.
  attn_mfma_kernel<<<dim3(2048), 128, 0, stream>>>(qT, kR, vF, krw, krh, attL);
  attnout_mfma_kernel<<<dim3(8, 4, 8), 256, 0, stream>>>(attL, w_attn, b_attn, out);
}

// Round 11
// 139.425 us; speedup vs baseline: 1.1545x; 1.1545x over previous
//
#include <hip/hip_runtime.h>
#include <hip/hip_bf16.h>

// AttentionConv2d: B=8, C_IN=256, H=W=32 (HW=1024), DK=DV=256, NH=8, DKH=DVH=32,
// C_OUT=512, 3x3 conv pad=1. fp32 storage in/out; bf16 intermediates + MFMA.
//
// Workspace (bf16 elements, EXACTLY 16 MB):
//   xT    [8 b][1024 l][256 ci]  @ 0          read by fused conv3+qkv
//   attL  [8 b][1024 l][256 ch]  @ 0          alias of xT (attn writes after fused done)
//   qT    [64 head][1024][32]    @ 2,097,152
//   kR    [64 head][1024][32]    @ 4,194,304
//   vF    [64 head][16 c][4 q][64 lane][8]  @ 6,291,456   (PV-fragment order)
// prep -> convqkv(fused) -> attn -> attnout.
// R22: attn k-split blocks. Grid 1024 x 256 thr (4 waves): waves {0,1} own
// chunks 0-7, waves {2,3} own chunks 8-15, for the same 64 q rows (wave&1
// selects the 32-q half; 2 subtiles/wave as R19). Per-block K/V fetch volume
// unchanged (R18's redundancy regression avoided) but waves/SIMD 2 -> 4
// (counters R21: 43% stall, no pipe >44%, occupancy grid-limited). Partial
// oacc/rsp from waves 2,3 combined via LDS aliased over the dead RWf table
// (element-major layout, conflict-free); logits have no max-sub so the
// combine is a pure sum. 3 block barriers, none in the k-loop.

typedef __hip_bfloat16 bf16;
typedef __attribute__((ext_vector_type(8))) short bf16x8;
typedef __attribute__((ext_vector_type(4))) float f32x4;

__device__ __forceinline__ float blo(unsigned int v) { return __uint_as_float(v << 16); }
__device__ __forceinline__ float bhi(unsigned int v) { return __uint_as_float(v & 0xffff0000u); }
__device__ __forceinline__ unsigned short f2bfbits(float f) {
  union { bf16 h; unsigned short u; } cv; cv.h = __float2bfloat16(f); return cv.u;
}
// v_cvt_pk_bf16_f32: dst.lo = bf16(lo), dst.hi = bf16(hi). RNE, 1 VALU op.
__device__ __forceinline__ unsigned int cvt_pk_bf16(float lo, float hi) {
  unsigned int r;
  asm("v_cvt_pk_bf16_f32 %0, %1, %2" : "=v"(r) : "v"(lo), "v"(hi));
  return r;
}
__device__ __forceinline__ float exp2_f(float x) {
#if __has_builtin(__builtin_amdgcn_exp2f)
  return __builtin_amdgcn_exp2f(x);
#else
  return exp2f(x);
#endif
}

// ---------------------------------------------------------------------------
// K0: prep — xT transpose to bf16 + w_out bf16 chunk-blocked into wob0/wob1.
// blocks 0..2047: xT; 2048..2083: w_out. grid 2084.
// ---------------------------------------------------------------------------
__global__ __launch_bounds__(256) void prep_kernel(
    const float* __restrict__ x, const float* __restrict__ wout,
    bf16* __restrict__ xT, bf16* __restrict__ wob0, bf16* __restrict__ wob1)
{
  int bid = blockIdx.x, tid = threadIdx.x;
  if (bid < 2048) {
    __shared__ float t[32 * 33];
    int b = bid >> 8, rem = bid & 255;
    int ci0 = (rem >> 5) * 32, l0 = (rem & 31) * 32;
    {
      int ciL = tid >> 3, lL4 = (tid & 7) * 4;
      float4 v = *(const float4*)(x + (size_t)(b * 256 + ci0 + ciL) * 1024 + l0 + lL4);
      t[ciL * 33 + lL4 + 0] = v.x; t[ciL * 33 + lL4 + 1] = v.y;
      t[ciL * 33 + lL4 + 2] = v.z; t[ciL * 33 + lL4 + 3] = v.w;
    }
    __syncthreads();
    {
      int lL = tid >> 3, cS = (tid & 7) * 4;
      unsigned int p0 = (unsigned int)f2bfbits(t[(cS + 0) * 33 + lL]) |
                        ((unsigned int)f2bfbits(t[(cS + 1) * 33 + lL]) << 16);
      unsigned int p1 = (unsigned int)f2bfbits(t[(cS + 2) * 33 + lL]) |
                        ((unsigned int)f2bfbits(t[(cS + 3) * 33 + lL]) << 16);
      uint2 u2; u2.x = p0; u2.y = p1;
      *(uint2*)(xT + ((size_t)(b * 1024) + l0 + lL) * 256 + ci0 + cS) = u2;
    }
  } else {
    int t0 = (bid - 2048) * 256 + tid;       // 0..9215
#pragma unroll
    for (int s = 0; s < 8; ++s) {
      int u = s * 9216 + t0;                 // dst uint4 index 0..73727
      int chunkblk = u / 2304;
      int within = u - chunkblk * 2304;
      int co63 = within / 36;
      int r = within - co63 * 36;            // kidx*4 + cig
      int kidx = r >> 2, cig = r & 3;
      int co = (chunkblk >> 3) * 64 + co63;
      int ci = (chunkblk & 7) * 32 + cig * 8;
      union { unsigned short h[8]; uint4 u4; } pk;
#pragma unroll
      for (int j = 0; j < 8; ++j)
        pk.h[j] = f2bfbits(wout[(size_t)(co * 256 + ci + j) * 9 + kidx]);
      bf16* dst = (chunkblk < 28) ? (wob0 + (size_t)chunkblk * 18432)
                                  : (wob1 + (size_t)(chunkblk - 28) * 18432);
      *(uint4*)(dst + (size_t)within * 8) = pk.u4;
    }
  }
}

// ---------------------------------------------------------------------------
// K1 (fused): blocks 0..255 = conv3 (3x3, MFMA shift-GEMM, prepacked weights);
// 256..1023 = qkv GEMM. Both only read xT -> co-resident, mutual latency hiding.
// V epilogue writes fragment-ordered vF (R17).
// ---------------------------------------------------------------------------
__global__ __launch_bounds__(256) void convqkv_kernel(
    const bf16* __restrict__ xT,
    const bf16* __restrict__ wob0, const bf16* __restrict__ wob1,
    const float* __restrict__ b_out, float* __restrict__ out,
    const float* __restrict__ wq, const float* __restrict__ b_qkv,
    bf16* __restrict__ qT, bf16* __restrict__ kR, bf16* __restrict__ vW)
{
  __shared__ __align__(16) short smem[27104];
  int tid = threadIdx.x, lane = tid & 63, wave = tid >> 6;
  int m16 = lane & 15, quad = lane >> 4;

  if (blockIdx.x < 256) {
    short* wS = smem;            // [64 co][296]
    short* xS = smem + 18944;    // [6 rows][34 cols][40]
    int bid = blockIdx.x;
    int rc = bid & 7, cotile = (bid >> 3) & 3, b = bid >> 5;
    int y0 = rc * 4;

    f32x4 acc[8];
#pragma unroll
    for (int t = 0; t < 8; ++t) acc[t] = (f32x4){0.f, 0.f, 0.f, 0.f};

    for (int ck = 0; ck < 8; ++ck) {
      __syncthreads();
      int cb = cotile * 8 + ck;
      const bf16* wbase = (cb < 28) ? (wob0 + (size_t)cb * 18432)
                                    : (wob1 + (size_t)(cb - 28) * 18432);
#pragma unroll
      for (int r = 0; r < 9; ++r) {
        int u = r * 256 + tid;
        *(uint4*)(wS + (u / 36) * 296 + (u % 36) * 8) = *(const uint4*)(wbase + (size_t)u * 8);
      }
#pragma unroll
      for (int r = 0; r < 3; ++r) {
        int u = r * 256 + tid;
        int pos = u >> 2, seg = u & 3;
        int row = pos >> 5, col = pos & 31;
        int gy = y0 - 1 + row;
        uint4 val = make_uint4(0u, 0u, 0u, 0u);
        if (gy >= 0 && gy < 32)
          val = *(const uint4*)(xT + ((size_t)(b * 1024) + gy * 32 + col) * 256 + ck * 32 + seg * 8);
        *(uint4*)(xS + (row * 34 + col + 1) * 40 + seg * 8) = val;
      }
      if (tid < 48) {
        int pos = tid >> 2, seg = tid & 3;
        int row = pos >> 1, side = pos & 1;
        *(uint4*)(xS + (row * 34 + side * 33) * 40 + seg * 8) = make_uint4(0u, 0u, 0u, 0u);
      }
      __syncthreads();
#pragma unroll
      for (int kidx = 0; kidx < 9; ++kidx) {
        int dy = kidx / 3, dx = kidx - dy * 3;
        bf16x8 af = *(const bf16x8*)(wS + (wave * 16 + m16) * 296 + kidx * 32 + quad * 8);
#pragma unroll
        for (int t = 0; t < 8; ++t) {
          int row = (t >> 1) + dy;
          int col = (t & 1) * 16 + m16 + dx;
          bf16x8 bf = *(const bf16x8*)(xS + (row * 34 + col) * 40 + quad * 8);
          acc[t] = __builtin_amdgcn_mfma_f32_16x16x32_bf16(af, bf, acc[t], 0, 0, 0);
        }
      }
    }

    int cob = cotile * 64 + wave * 16 + quad * 4;
#pragma unroll
    for (int i = 0; i < 4; ++i) {
      float bv = b_out[cob + i];
#pragma unroll
      for (int t = 0; t < 8; ++t) {
        int y = y0 + (t >> 1), xc = (t & 1) * 16 + m16;
        out[((size_t)(b * 512) + cob + i) * 1024 + y * 32 + xc] = acc[t][i] + bv;
      }
    }
  } else {
    short* aS = smem;            // [64][72]
    short* bS = smem + 4608;     // [128][72]
    int bid2 = blockIdx.x - 256;
    int ltile = bid2 & 7;
    int rest = bid2 >> 3;
    int ctile = rest % 12;
    int b = rest / 12;
    int l0 = ltile * 128;
    int cbase = ctile * 64;

    f32x4 acc[8];
#pragma unroll
    for (int t = 0; t < 8; ++t) acc[t] = (f32x4){0.f, 0.f, 0.f, 0.f};

    for (int ck = 0; ck < 4; ++ck) {
      __syncthreads();
#pragma unroll
      for (int r = 0; r < 4; ++r) {
        int u = r * 256 + tid;
        int c = u >> 4, s4 = u & 15;
        float4 v = *(const float4*)(wq + (size_t)(cbase + c) * 256 + ck * 64 + s4 * 4);
        unsigned int p0 = (unsigned int)f2bfbits(v.x) | ((unsigned int)f2bfbits(v.y) << 16);
        unsigned int p1 = (unsigned int)f2bfbits(v.z) | ((unsigned int)f2bfbits(v.w) << 16);
        uint2 u2; u2.x = p0; u2.y = p1;
        *(uint2*)(aS + c * 72 + s4 * 4) = u2;
      }
#pragma unroll
      for (int r = 0; r < 4; ++r) {
        int u = r * 256 + tid;
        int l = u >> 3, seg = u & 7;
        *(uint4*)(bS + l * 72 + seg * 8) =
            *(const uint4*)(xT + ((size_t)(b * 1024) + l0 + l) * 256 + ck * 64 + seg * 8);
      }
      __syncthreads();
#pragma unroll
      for (int ks = 0; ks < 2; ++ks) {
        bf16x8 af = *(const bf16x8*)(aS + (wave * 16 + m16) * 72 + ks * 32 + quad * 8);
#pragma unroll
        for (int t = 0; t < 8; ++t) {
          bf16x8 bf = *(const bf16x8*)(bS + (t * 16 + m16) * 72 + ks * 32 + quad * 8);
          acc[t] = __builtin_amdgcn_mfma_f32_16x16x32_bf16(af, bf, acc[t], 0, 0, 0);
        }
      }
    }

    __syncthreads();
    short* ldsT = smem + wave * 3072;
    int cb = cbase + wave * 16;
    bool isq = (ctile < 4);
    float bv[4];
#pragma unroll
    for (int i = 0; i < 4; ++i) bv[i] = b_qkv[cb + quad * 4 + i];
#pragma unroll
    for (int t = 0; t < 8; ++t) {
#pragma unroll
      for (int i = 0; i < 4; ++i) {
        float v = acc[t][i] + bv[i];
        if (isq) v *= 0.17677669529663689f;  // 32^-0.5, pre-rel-logits
        ldsT[(t * 16 + m16) * 24 + quad * 4 + i] = (short)f2bfbits(v);
      }
    }
    if (ctile < 8) {
      bf16* dst = isq ? qT : kR;
      int coff = isq ? cb : cb - 256;
#pragma unroll
      for (int rep = 0; rep < 4; ++rep) {
        int u = rep * 64 + lane;
        int l = u >> 1, half = u & 1;
        int c0 = coff + half * 8;
        int head = b * 8 + (c0 >> 5), d0 = c0 & 31;
        *(uint4*)(dst + ((size_t)head * 1024 + l0 + l) * 32 + d0) =
            *(const uint4*)(ldsT + l * 24 + half * 8);
      }
    } else {
      // fragment-ordered vF writes (R17).
      int dcol = lane >> 2, lg = lane & 3;
      int c2 = (cb - 512) + dcol;
      int head = b * 8 + (c2 >> 5), gd = c2 & 31;
      int dt = gd >> 4, m16v = gd & 15;
      int cch = ltile * 2 + (lg >> 1);
      int ksv = lg & 1;
      bf16* vbase = vW + (size_t)head * 32768 + cch * 2048 + (dt * 2 + ksv) * 512 + m16v * 8;
#pragma unroll
      for (int s = 0; s < 4; ++s) {
#pragma unroll
        for (int p = 0; p < 4; ++p) {
          int j0 = lg * 32 + s * 8 + p * 2;
          unsigned int u0 = (unsigned short)ldsT[j0 * 24 + dcol];
          unsigned int u1 = (unsigned short)ldsT[(j0 + 1) * 24 + dcol];
          unsigned int w = u0 | (u1 << 16);
          int quadp = (s & 1) * 2 + (p >> 1);
          int jj = (p & 1) * 2 + (s >> 1) * 4;
          *(unsigned int*)(vbase + quadp * 128 + jj) = w;
        }
      }
    }
  }
}

// ---------------------------------------------------------------------------
// K3: MFMA attention, R22 k-split. Grid 1024 x 256 thr (4 waves). qw = wave&1
// selects the 32-q half (2 subtiles, R19 layout); kw = wave>>1 selects the
// chunk half (kw*8 .. kw*8+8). Per-block K/V fetch volume = R19 (2 waves per
// chunk), waves/SIMD 2 -> 4. Tables via MFMA (wave w builds m-tile w).
// Partials: waves kw==1 write oacc/rsp to LDS aliased over the dead RWf
// region (element-major, conflict-free); barrier; waves kw==0 combine (pure
// sum — no max-sub in this softmax) and run the R19 epilogue.
// LDS: RWf f32 [64][68] @0 (17408; dead after gather -> pO @0 8192, pR @8192
// 1024); RHf f32 [64][68] @17408. Total 34816 B.
// ---------------------------------------------------------------------------
__global__ __launch_bounds__(256) void attn_mfma_kernel(
    const bf16* __restrict__ qT, const bf16* __restrict__ kR, const bf16* __restrict__ vW,
    const float* __restrict__ krw, const float* __restrict__ krh,
    bf16* __restrict__ attL)
{
  __shared__ __align__(16) char smem[34816];
  float* RWf = (float*)smem;             // [64 m][68]  (prologue only)
  float* RHf = (float*)(smem + 17408);   // [64 m][68]  (read-only in loop)
  float* pO  = (float*)smem;             // [16 e][128 (qw*64+lane)] alias, post-loop
  float* pR  = (float*)(smem + 8192);    // [2 sub][128] alias, post-loop

  const float L2E = 1.4426950408889634f;

  int tid = threadIdx.x;
  int lane = tid & 63, wave = tid >> 6;      // wave in {0..3}
  int qw = wave & 1, kw = wave >> 1;
  int m16 = lane & 15, quad = lane >> 4;
  int bid = blockIdx.x;
  // same head -> same blockIdx mod 8 -> same XCD (round-robin heuristic)
  int head = ((bid & 7) << 3) | ((bid >> 3) & 7);
  int qt = bid >> 6;                 // 0..15, 64 q rows per block
  int row0 = qt * 64;
  int b = head >> 3, h = head & 7;

  // ---- rel-logit tables via MFMA (wave w builds m-tile w) ----
  {
    int mtile = wave;
    int mrow = mtile * 16 + m16;
    bool valid = (mrow < 63);
    float4 w0 = make_float4(0.f, 0.f, 0.f, 0.f), w1 = w0, h0 = w0, h1 = w0;
    if (valid) {
      w0 = *(const float4*)(krw + mrow * 32 + quad * 8);
      w1 = *(const float4*)(krw + mrow * 32 + quad * 8 + 4);
      h0 = *(const float4*)(krh + mrow * 32 + quad * 8);
      h1 = *(const float4*)(krh + mrow * 32 + quad * 8 + 4);
    }
    union { unsigned int w[4]; bf16x8 v; } aw, ah;
    aw.w[0] = cvt_pk_bf16(w0.x * L2E, w0.y * L2E);
    aw.w[1] = cvt_pk_bf16(w0.z * L2E, w0.w * L2E);
    aw.w[2] = cvt_pk_bf16(w1.x * L2E, w1.y * L2E);
    aw.w[3] = cvt_pk_bf16(w1.z * L2E, w1.w * L2E);
    ah.w[0] = cvt_pk_bf16(h0.x * L2E, h0.y * L2E);
    ah.w[1] = cvt_pk_bf16(h0.z * L2E, h0.w * L2E);
    ah.w[2] = cvt_pk_bf16(h1.x * L2E, h1.y * L2E);
    ah.w[3] = cvt_pk_bf16(h1.z * L2E, h1.w * L2E);
#pragma unroll
    for (int nt = 0; nt < 4; ++nt) {
      bf16x8 qf = *(const bf16x8*)(
          qT + ((size_t)head * 1024 + row0 + nt * 16 + m16) * 32 + quad * 8);
      f32x4 z = (f32x4){0.f, 0.f, 0.f, 0.f};
      f32x4 dw = __builtin_amdgcn_mfma_f32_16x16x32_bf16(aw.v, qf, z, 0, 0, 0);
      f32x4 dh = __builtin_amdgcn_mfma_f32_16x16x32_bf16(ah.v, qf, z, 0, 0, 0);
#pragma unroll
      for (int i = 0; i < 4; ++i) {
        int mr = mtile * 16 + quad * 4 + i;     // D row = m (rel index)
        RWf[mr * 68 + nt * 16 + m16] = dw[i];
        RHf[mr * 68 + nt * 16 + m16] = dh[i];
      }
    }
  }
  __syncthreads();   // tables complete

  // ---- Q fragments (B-operand) + chunk-invariant RW registers, per subtile
  bf16x8 afrag[2];
  float rwreg[2][2][4];
  int qloc0 = qw * 32 + m16;         // sub 0; sub 1 adds 16
#pragma unroll
  for (int sub = 0; sub < 2; ++sub) {
    int qloc = qloc0 + sub * 16;
    afrag[sub] = *(const bf16x8*)(
        qT + ((size_t)head * 1024 + row0 + qloc) * 32 + quad * 8);
    int qm = qloc & 31;
#pragma unroll
    for (int par = 0; par < 2; ++par)
#pragma unroll
      for (int i = 0; i < 4; ++i)
        rwreg[sub][par][i] = RWf[(par * 16 + quad * 4 + i - qm + 31) * 68 + qloc];
  }
  __syncthreads();   // all RWf gathers done -> pO/pR alias of RWf is safe

  int qy = qt * 2 + qw;              // (qloc>>5) == qw for both subtiles
  const float* rhp0 = RHf + (31 - qy) * 68 + qloc0;        // +c*2*68 per chunk
  const float* rhp1 = rhp0 + 16;                           // sub 1 column

  // per-lane global fragment pointers (wave-independent: subs share fetches)
  const bf16* kp = kR + (size_t)head * 32768 + m16 * 32 + quad * 8;   // +c*2048 +t*512
  const bf16* vp = vW + (size_t)head * 32768 + lane * 8;              // +c*2048 +(dt*2+ks)*512

  f32x4 oacc[2][2];
#pragma unroll
  for (int sub = 0; sub < 2; ++sub) {
    oacc[sub][0] = (f32x4){0.f, 0.f, 0.f, 0.f};
    oacc[sub][1] = (f32x4){0.f, 0.f, 0.f, 0.f};
  }
  float rsp[2] = {0.f, 0.f};

  int c0 = kw * 8;
#pragma unroll 1
  for (int c = c0; c < c0 + 8; ++c) {
    // issue all 8 shared fragment loads up front (latency overlaps exp below)
    union { uint4 u; bf16x8 v; } kf[4], vf[4];
#pragma unroll
    for (int t = 0; t < 4; ++t)
      kf[t].u = *(const uint4*)(kp + c * 2048 + t * 512);
#pragma unroll
    for (int q = 0; q < 4; ++q)         // q = dt*2 + ks
      vf[q].u = *(const uint4*)(vp + c * 2048 + q * 512);

    // RH for this chunk (per sub column; rows uniform per wave)
    float rh[2][2];
    rh[0][0] = rhp0[(c * 2 + 0) * 68];  rh[0][1] = rhp0[(c * 2 + 1) * 68];
    rh[1][0] = rhp1[(c * 2 + 0) * 68];  rh[1][1] = rhp1[(c * 2 + 1) * 68];

    // QK^T swapped: A = K frag (rows=keys), B = Qfrag[sub] (cols=q)
    f32x4 sacc[2][4];
#pragma unroll
    for (int t = 0; t < 4; ++t) {
      f32x4 z = (f32x4){0.f, 0.f, 0.f, 0.f};
#pragma unroll
      for (int sub = 0; sub < 2; ++sub)
        sacc[sub][t] = __builtin_amdgcn_mfma_f32_16x16x32_bf16(kf[t].v, afrag[sub], z, 0, 0, 0);
    }

    // softmax numerators in-register (lane q = qloc, key = t*16+quad*4+i)
    unsigned int pk[2][4][2];
#pragma unroll
    for (int sub = 0; sub < 2; ++sub) {
#pragma unroll
      for (int t = 0; t < 4; ++t) {
        float rhv = rh[sub][t >> 1];
        float e0 = exp2_f(fmaf(sacc[sub][t][0], L2E, rwreg[sub][t & 1][0] + rhv));
        float e1 = exp2_f(fmaf(sacc[sub][t][1], L2E, rwreg[sub][t & 1][1] + rhv));
        float e2 = exp2_f(fmaf(sacc[sub][t][2], L2E, rwreg[sub][t & 1][2] + rhv));
        float e3 = exp2_f(fmaf(sacc[sub][t][3], L2E, rwreg[sub][t & 1][3] + rhv));
        rsp[sub] += (e0 + e1) + (e2 + e3);
        pk[sub][t][0] = cvt_pk_bf16(e0, e1);
        pk[sub][t][1] = cvt_pk_bf16(e2, e3);
      }
    }

    // PV: O^T = mfma(Vfrag, P^T). kappa = ks*32 + (j>>2)*16 + quad*4 + (j&3).
#pragma unroll
    for (int ks = 0; ks < 2; ++ks) {
#pragma unroll
      for (int sub = 0; sub < 2; ++sub) {
        union { unsigned int w[4]; bf16x8 v; } pf;
        pf.w[0] = pk[sub][2 * ks][0];     pf.w[1] = pk[sub][2 * ks][1];
        pf.w[2] = pk[sub][2 * ks + 1][0]; pf.w[3] = pk[sub][2 * ks + 1][1];
#pragma unroll
        for (int dt = 0; dt < 2; ++dt) {
          oacc[sub][dt] = __builtin_amdgcn_mfma_f32_16x16x32_bf16(
              vf[dt * 2 + ks].v, pf.v, oacc[sub][dt], 0, 0, 0);
        }
      }
    }
  }

  // ---- k-half combine: waves kw==1 publish partials over dead RWf region ----
  if (kw == 1) {
#pragma unroll
    for (int sub = 0; sub < 2; ++sub) {
#pragma unroll
      for (int dt = 0; dt < 2; ++dt)
#pragma unroll
        for (int i = 0; i < 4; ++i)
          pO[(((sub * 2 + dt) * 4 + i) * 128) + qw * 64 + lane] = oacc[sub][dt][i];
      pR[sub * 128 + qw * 64 + lane] = rsp[sub];
    }
  }
  __syncthreads();
  if (kw == 0) {
#pragma unroll
    for (int sub = 0; sub < 2; ++sub) {
#pragma unroll
      for (int dt = 0; dt < 2; ++dt)
#pragma unroll
        for (int i = 0; i < 4; ++i)
          oacc[sub][dt][i] += pO[(((sub * 2 + dt) * 4 + i) * 128) + qw * 64 + lane];
      rsp[sub] += pR[sub * 128 + qw * 64 + lane];
    }

    // ---- epilogue: reduce row-sums across quads, normalize, store ----
#pragma unroll
    for (int sub = 0; sub < 2; ++sub) {
      rsp[sub] += __shfl_xor(rsp[sub], 16, 64);
      rsp[sub] += __shfl_xor(rsp[sub], 32, 64);
      float invs = 1.0f / rsp[sub];
      int grow = row0 + qloc0 + sub * 16;
#pragma unroll
      for (int dt = 0; dt < 2; ++dt) {
        uint2 st;
        st.x = cvt_pk_bf16(oacc[sub][dt][0] * invs, oacc[sub][dt][1] * invs);
        st.y = cvt_pk_bf16(oacc[sub][dt][2] * invs, oacc[sub][dt][3] * invs);
        *(uint2*)(attL + ((size_t)b * 1024 + grow) * 256 + h * 32 + dt * 16 + quad * 4) = st;
      }
    }
  }
}

// ---------------------------------------------------------------------------
// K4: attnout 1x1 conv as MFMA GEMM 256 x 1024 x 256 per batch. (R6 version)
// Runs last; overwrites the d_out ch256+ regions that hosted wo_bf.
// ---------------------------------------------------------------------------
__global__ __launch_bounds__(256) void attnout_mfma_kernel(
    const bf16* __restrict__ attL, const float* __restrict__ w, const float* __restrict__ bias,
    float* __restrict__ out)
{
  __shared__ __align__(16) short smem[13824];
  short* aS = smem;            // [64 co][72]
  short* bS = smem + 4608;     // [128 l][72]

  int tid = threadIdx.x, lane = tid & 63, wave = tid >> 6;
  int m16 = lane & 15, quad = lane >> 4;
  int l0 = blockIdx.x * 128;
  int cotile = blockIdx.y;
  int b = blockIdx.z;
  int cbase = cotile * 64;

  f32x4 acc[8];
#pragma unroll
  for (int t = 0; t < 8; ++t) acc[t] = (f32x4){0.f, 0.f, 0.f, 0.f};

  for (int ck = 0; ck < 4; ++ck) {
    __syncthreads();
#pragma unroll
    for (int r = 0; r < 4; ++r) {
      int u = r * 256 + tid;
      int c = u >> 4, s4 = u & 15;
      float4 v = *(const float4*)(w + (size_t)(cbase + c) * 256 + ck * 64 + s4 * 4);
      unsigned int p0 = (unsigned int)f2bfbits(v.x) | ((unsigned int)f2bfbits(v.y) << 16);
      unsigned int p1 = (unsigned int)f2bfbits(v.z) | ((unsigned int)f2bfbits(v.w) << 16);
      uint2 u2; u2.x = p0; u2.y = p1;
      *(uint2*)(aS + c * 72 + s4 * 4) = u2;
    }
#pragma unroll
    for (int r = 0; r < 4; ++r) {
      int u = r * 256 + tid;
      int l = u >> 3, seg = u & 7;
      *(uint4*)(bS + l * 72 + seg * 8) =
          *(const uint4*)(attL + ((size_t)(b * 1024) + l0 + l) * 256 + ck * 64 + seg * 8);
    }
    __syncthreads();
#pragma unroll
    for (int ks = 0; ks < 2; ++ks) {
      bf16x8 af = *(const bf16x8*)(aS + (wave * 16 + m16) * 72 + ks * 32 + quad * 8);
#pragma unroll
      for (int t = 0; t < 8; ++t) {
        bf16x8 bf = *(const bf16x8*)(bS + (t * 16 + m16) * 72 + ks * 32 + quad * 8);
        acc[t] = __builtin_amdgcn_mfma_f32_16x16x32_bf16(af, bf, acc[t], 0, 0, 0);
      }
    }
  }

  int co = cbase + wave * 16 + quad * 4;
#pragma unroll
  for (int i = 0; i < 4; ++i) {
    float bv = bias[co + i];
    size_t obase = ((size_t)(b * 512) + 256 + co + i) * 1024 + l0;
#pragma unroll
    for (int t = 0; t < 8; ++t)
      out[obase + t * 16 + m16] = acc[t][i] + bv;
  }
}

// ---------------------------------------------------------------------------
extern "C" void kernel_launch(void* const* d_in, const int* in_sizes, int n_in,
                              void* d_out, int out_size, void* d_ws, size_t ws_size,
                              hipStream_t stream) {
  const float* x      = (const float*)d_in[0];
  const float* w_qkv  = (const float*)d_in[1];
  const float* b_qkv  = (const float*)d_in[2];
  const float* w_attn = (const float*)d_in[3];
  const float* b_attn = (const float*)d_in[4];
  const float* w_out  = (const float*)d_in[5];
  const float* b_out  = (const float*)d_in[6];
  const float* krw    = (const float*)d_in[7];
  const float* krh    = (const float*)d_in[8];
  float* out = (float*)d_out;

  bf16* ws    = (bf16*)d_ws;
  bf16* xT    = ws;                 // [0, 2,097,152)  read by fused conv3+qkv
  bf16* attL  = ws;                 // alias of xT     (attn -> attnout, after fused)
  bf16* qT    = ws + 2097152;       // [2,097,152, 4,194,304)
  bf16* kR    = ws + 4194304;       // [4,194,304, 6,291,456)
  bf16* vF    = ws + 6291456;       // [6,291,456, 8,388,608)  fragment-ordered V

  // wo_bf in d_out's attention half (dead until attnout overwrites it)
  bf16* wob0 = (bf16*)(out + (size_t)(0 * 512 + 256) * 1024);
  bf16* wob1 = (bf16*)(out + (size_t)(1 * 512 + 256) * 1024);

  prep_kernel<<<dim3(2084), 256, 0, stream>>>(x, w_out, xT, wob0, wob1);
  convqkv_kernel<<<dim3(1024), 256, 0, stream>>>(xT, wob0, wob1, b_out, out,
                                                 w_qkv, b_qkv, qT, kR, vF);
  attn_mfma_kernel<<<dim3(1024), 256, 0, stream>>>(qT, kR, vF, krw, krh, attL);
  attnout_mfma_kernel<<<dim3(8, 4, 8), 256, 0, stream>>>(attL, w_attn, b_attn, out);
}

// Round 12
// 136.909 us; speedup vs baseline: 1.1757x; 1.0184x over previous
//
#include <hip/hip_runtime.h>
#include <hip/hip_bf16.h>

// AttentionConv2d: B=8, C_IN=256, H=W=32 (HW=1024), DK=DV=256, NH=8, DKH=DVH=32,
// C_OUT=512, 3x3 conv pad=1. fp32 storage in/out; bf16 intermediates + MFMA.
//
// Workspace (bf16 elements, EXACTLY 16 MB):
//   xT    [8 b][1024 l][256 ci]  @ 0          read by fused conv3+qkv
//   attL  [8 b][1024 l][256 ch]  @ 0          alias of xT (attn writes after fused done)
//   qT    [64 head][1024][32]    @ 2,097,152
//   kR    [64 head][1024][32]    @ 4,194,304
//   vF    [64 head][16 c][4 q][64 lane][8]  @ 6,291,456   (PV-fragment order)
// prep -> convqkv(fused) -> attn -> attnout.
// R23: attn = R19 (best, 138.5); NEW: wq pre-converted to bf16 ONCE by prep
// into wqb (384 KB, hosted in d_out batch-2's attention half — dead until
// attnout overwrites it, same trick as wob0/wob1). qkv A-staging becomes 2
// uint4 copies instead of float4 + 16 f2bfbits + packs per ck per block
// (the same wq slice was being re-converted by 64 blocks). Numerically
// identical (same conversion, done once).

typedef __hip_bfloat16 bf16;
typedef __attribute__((ext_vector_type(8))) short bf16x8;
typedef __attribute__((ext_vector_type(4))) float f32x4;

__device__ __forceinline__ float blo(unsigned int v) { return __uint_as_float(v << 16); }
__device__ __forceinline__ float bhi(unsigned int v) { return __uint_as_float(v & 0xffff0000u); }
__device__ __forceinline__ unsigned short f2bfbits(float f) {
  union { bf16 h; unsigned short u; } cv; cv.h = __float2bfloat16(f); return cv.u;
}
// v_cvt_pk_bf16_f32: dst.lo = bf16(lo), dst.hi = bf16(hi). RNE, 1 VALU op.
__device__ __forceinline__ unsigned int cvt_pk_bf16(float lo, float hi) {
  unsigned int r;
  asm("v_cvt_pk_bf16_f32 %0, %1, %2" : "=v"(r) : "v"(lo), "v"(hi));
  return r;
}
__device__ __forceinline__ float exp2_f(float x) {
#if __has_builtin(__builtin_amdgcn_exp2f)
  return __builtin_amdgcn_exp2f(x);
#else
  return exp2f(x);
#endif
}

// ---------------------------------------------------------------------------
// K0: prep — xT transpose to bf16 + w_out chunk-blocked (wob0/wob1) + wq bf16
// pre-conversion (wqb). blocks 0..2047: xT; 2048..2083: w_out; 2084..2107: wq.
// grid 2108.
// ---------------------------------------------------------------------------
__global__ __launch_bounds__(256) void prep_kernel(
    const float* __restrict__ x, const float* __restrict__ wout,
    const float* __restrict__ wq,
    bf16* __restrict__ xT, bf16* __restrict__ wob0, bf16* __restrict__ wob1,
    bf16* __restrict__ wqb)
{
  int bid = blockIdx.x, tid = threadIdx.x;
  if (bid < 2048) {
    __shared__ float t[32 * 33];
    int b = bid >> 8, rem = bid & 255;
    int ci0 = (rem >> 5) * 32, l0 = (rem & 31) * 32;
    {
      int ciL = tid >> 3, lL4 = (tid & 7) * 4;
      float4 v = *(const float4*)(x + (size_t)(b * 256 + ci0 + ciL) * 1024 + l0 + lL4);
      t[ciL * 33 + lL4 + 0] = v.x; t[ciL * 33 + lL4 + 1] = v.y;
      t[ciL * 33 + lL4 + 2] = v.z; t[ciL * 33 + lL4 + 3] = v.w;
    }
    __syncthreads();
    {
      int lL = tid >> 3, cS = (tid & 7) * 4;
      unsigned int p0 = (unsigned int)f2bfbits(t[(cS + 0) * 33 + lL]) |
                        ((unsigned int)f2bfbits(t[(cS + 1) * 33 + lL]) << 16);
      unsigned int p1 = (unsigned int)f2bfbits(t[(cS + 2) * 33 + lL]) |
                        ((unsigned int)f2bfbits(t[(cS + 3) * 33 + lL]) << 16);
      uint2 u2; u2.x = p0; u2.y = p1;
      *(uint2*)(xT + ((size_t)(b * 1024) + l0 + lL) * 256 + ci0 + cS) = u2;
    }
  } else if (bid < 2084) {
    int t0 = (bid - 2048) * 256 + tid;       // 0..9215
#pragma unroll
    for (int s = 0; s < 8; ++s) {
      int u = s * 9216 + t0;                 // dst uint4 index 0..73727
      int chunkblk = u / 2304;
      int within = u - chunkblk * 2304;
      int co63 = within / 36;
      int r = within - co63 * 36;            // kidx*4 + cig
      int kidx = r >> 2, cig = r & 3;
      int co = (chunkblk >> 3) * 64 + co63;
      int ci = (chunkblk & 7) * 32 + cig * 8;
      union { unsigned short h[8]; uint4 u4; } pk;
#pragma unroll
      for (int j = 0; j < 8; ++j)
        pk.h[j] = f2bfbits(wout[(size_t)(co * 256 + ci + j) * 9 + kidx]);
      bf16* dst = (chunkblk < 28) ? (wob0 + (size_t)chunkblk * 18432)
                                  : (wob1 + (size_t)(chunkblk - 28) * 18432);
      *(uint4*)(dst + (size_t)within * 8) = pk.u4;
    }
  } else {
    // wq (768x256 f32) -> wqb bf16, linear. 24 blocks x 256 thr x 32 elems.
    int idx = (bid - 2084) * 256 + tid;      // 0..6143
    const float* src = wq + (size_t)idx * 32;
    bf16* dst = wqb + (size_t)idx * 32;
#pragma unroll
    for (int g = 0; g < 4; ++g) {
      float4 a = *(const float4*)(src + g * 8);
      float4 c = *(const float4*)(src + g * 8 + 4);
      union { unsigned int w[4]; uint4 u4; } pk;
      pk.w[0] = (unsigned int)f2bfbits(a.x) | ((unsigned int)f2bfbits(a.y) << 16);
      pk.w[1] = (unsigned int)f2bfbits(a.z) | ((unsigned int)f2bfbits(a.w) << 16);
      pk.w[2] = (unsigned int)f2bfbits(c.x) | ((unsigned int)f2bfbits(c.y) << 16);
      pk.w[3] = (unsigned int)f2bfbits(c.z) | ((unsigned int)f2bfbits(c.w) << 16);
      *(uint4*)(dst + g * 8) = pk.u4;
    }
  }
}

// ---------------------------------------------------------------------------
// K1 (fused): blocks 0..255 = conv3 (3x3, MFMA shift-GEMM, prepacked weights);
// 256..1023 = qkv GEMM (A from pre-converted wqb bf16). Both only read xT ->
// co-resident, mutual latency hiding. V epilogue writes fragment-ordered vF.
// ---------------------------------------------------------------------------
__global__ __launch_bounds__(256) void convqkv_kernel(
    const bf16* __restrict__ xT,
    const bf16* __restrict__ wob0, const bf16* __restrict__ wob1,
    const float* __restrict__ b_out, float* __restrict__ out,
    const bf16* __restrict__ wqb, const float* __restrict__ b_qkv,
    bf16* __restrict__ qT, bf16* __restrict__ kR, bf16* __restrict__ vW)
{
  __shared__ __align__(16) short smem[27104];
  int tid = threadIdx.x, lane = tid & 63, wave = tid >> 6;
  int m16 = lane & 15, quad = lane >> 4;

  if (blockIdx.x < 256) {
    short* wS = smem;            // [64 co][296]
    short* xS = smem + 18944;    // [6 rows][34 cols][40]
    int bid = blockIdx.x;
    int rc = bid & 7, cotile = (bid >> 3) & 3, b = bid >> 5;
    int y0 = rc * 4;

    f32x4 acc[8];
#pragma unroll
    for (int t = 0; t < 8; ++t) acc[t] = (f32x4){0.f, 0.f, 0.f, 0.f};

    for (int ck = 0; ck < 8; ++ck) {
      __syncthreads();
      int cb = cotile * 8 + ck;
      const bf16* wbase = (cb < 28) ? (wob0 + (size_t)cb * 18432)
                                    : (wob1 + (size_t)(cb - 28) * 18432);
#pragma unroll
      for (int r = 0; r < 9; ++r) {
        int u = r * 256 + tid;
        *(uint4*)(wS + (u / 36) * 296 + (u % 36) * 8) = *(const uint4*)(wbase + (size_t)u * 8);
      }
#pragma unroll
      for (int r = 0; r < 3; ++r) {
        int u = r * 256 + tid;
        int pos = u >> 2, seg = u & 3;
        int row = pos >> 5, col = pos & 31;
        int gy = y0 - 1 + row;
        uint4 val = make_uint4(0u, 0u, 0u, 0u);
        if (gy >= 0 && gy < 32)
          val = *(const uint4*)(xT + ((size_t)(b * 1024) + gy * 32 + col) * 256 + ck * 32 + seg * 8);
        *(uint4*)(xS + (row * 34 + col + 1) * 40 + seg * 8) = val;
      }
      if (tid < 48) {
        int pos = tid >> 2, seg = tid & 3;
        int row = pos >> 1, side = pos & 1;
        *(uint4*)(xS + (row * 34 + side * 33) * 40 + seg * 8) = make_uint4(0u, 0u, 0u, 0u);
      }
      __syncthreads();
#pragma unroll
      for (int kidx = 0; kidx < 9; ++kidx) {
        int dy = kidx / 3, dx = kidx - dy * 3;
        bf16x8 af = *(const bf16x8*)(wS + (wave * 16 + m16) * 296 + kidx * 32 + quad * 8);
#pragma unroll
        for (int t = 0; t < 8; ++t) {
          int row = (t >> 1) + dy;
          int col = (t & 1) * 16 + m16 + dx;
          bf16x8 bf = *(const bf16x8*)(xS + (row * 34 + col) * 40 + quad * 8);
          acc[t] = __builtin_amdgcn_mfma_f32_16x16x32_bf16(af, bf, acc[t], 0, 0, 0);
        }
      }
    }

    int cob = cotile * 64 + wave * 16 + quad * 4;
#pragma unroll
    for (int i = 0; i < 4; ++i) {
      float bv = b_out[cob + i];
#pragma unroll
      for (int t = 0; t < 8; ++t) {
        int y = y0 + (t >> 1), xc = (t & 1) * 16 + m16;
        out[((size_t)(b * 512) + cob + i) * 1024 + y * 32 + xc] = acc[t][i] + bv;
      }
    }
  } else {
    short* aS = smem;            // [64][72]
    short* bS = smem + 4608;     // [128][72]
    int bid2 = blockIdx.x - 256;
    int ltile = bid2 & 7;
    int rest = bid2 >> 3;
    int ctile = rest % 12;
    int b = rest / 12;
    int l0 = ltile * 128;
    int cbase = ctile * 64;

    f32x4 acc[8];
#pragma unroll
    for (int t = 0; t < 8; ++t) acc[t] = (f32x4){0.f, 0.f, 0.f, 0.f};

    for (int ck = 0; ck < 4; ++ck) {
      __syncthreads();
#pragma unroll
      for (int r = 0; r < 2; ++r) {
        int u = r * 256 + tid;
        int c = u >> 3, s8 = u & 7;
        *(uint4*)(aS + c * 72 + s8 * 8) =
            *(const uint4*)(wqb + (size_t)(cbase + c) * 256 + ck * 64 + s8 * 8);
      }
#pragma unroll
      for (int r = 0; r < 4; ++r) {
        int u = r * 256 + tid;
        int l = u >> 3, seg = u & 7;
        *(uint4*)(bS + l * 72 + seg * 8) =
            *(const uint4*)(xT + ((size_t)(b * 1024) + l0 + l) * 256 + ck * 64 + seg * 8);
      }
      __syncthreads();
#pragma unroll
      for (int ks = 0; ks < 2; ++ks) {
        bf16x8 af = *(const bf16x8*)(aS + (wave * 16 + m16) * 72 + ks * 32 + quad * 8);
#pragma unroll
        for (int t = 0; t < 8; ++t) {
          bf16x8 bf = *(const bf16x8*)(bS + (t * 16 + m16) * 72 + ks * 32 + quad * 8);
          acc[t] = __builtin_amdgcn_mfma_f32_16x16x32_bf16(af, bf, acc[t], 0, 0, 0);
        }
      }
    }

    __syncthreads();
    short* ldsT = smem + wave * 3072;
    int cb = cbase + wave * 16;
    bool isq = (ctile < 4);
    float bv[4];
#pragma unroll
    for (int i = 0; i < 4; ++i) bv[i] = b_qkv[cb + quad * 4 + i];
#pragma unroll
    for (int t = 0; t < 8; ++t) {
#pragma unroll
      for (int i = 0; i < 4; ++i) {
        float v = acc[t][i] + bv[i];
        if (isq) v *= 0.17677669529663689f;  // 32^-0.5, pre-rel-logits
        ldsT[(t * 16 + m16) * 24 + quad * 4 + i] = (short)f2bfbits(v);
      }
    }
    if (ctile < 8) {
      bf16* dst = isq ? qT : kR;
      int coff = isq ? cb : cb - 256;
#pragma unroll
      for (int rep = 0; rep < 4; ++rep) {
        int u = rep * 64 + lane;
        int l = u >> 1, half = u & 1;
        int c0 = coff + half * 8;
        int head = b * 8 + (c0 >> 5), d0 = c0 & 31;
        *(uint4*)(dst + ((size_t)head * 1024 + l0 + l) * 32 + d0) =
            *(const uint4*)(ldsT + l * 24 + half * 8);
      }
    } else {
      // fragment-ordered vF writes (R17).
      int dcol = lane >> 2, lg = lane & 3;
      int c2 = (cb - 512) + dcol;
      int head = b * 8 + (c2 >> 5), gd = c2 & 31;
      int dt = gd >> 4, m16v = gd & 15;
      int cch = ltile * 2 + (lg >> 1);
      int ksv = lg & 1;
      bf16* vbase = vW + (size_t)head * 32768 + cch * 2048 + (dt * 2 + ksv) * 512 + m16v * 8;
#pragma unroll
      for (int s = 0; s < 4; ++s) {
#pragma unroll
        for (int p = 0; p < 4; ++p) {
          int j0 = lg * 32 + s * 8 + p * 2;
          unsigned int u0 = (unsigned short)ldsT[j0 * 24 + dcol];
          unsigned int u1 = (unsigned short)ldsT[(j0 + 1) * 24 + dcol];
          unsigned int w = u0 | (u1 << 16);
          int quadp = (s & 1) * 2 + (p >> 1);
          int jj = (p & 1) * 2 + (s >> 1) * 4;
          *(unsigned int*)(vbase + quadp * 128 + jj) = w;
        }
      }
    }
  }
}

// ---------------------------------------------------------------------------
// K3: MFMA attention, R19 form (best). Grid 1024 x 128 threads (2 waves),
// each wave owns 32 q rows (2 subtiles sharing every K/V fetch). Prologue:
// rel-logit tables via MFMA (one barrier). K-loop: zero barriers, direct
// global K (kR) + V (vF fragment-order) reads, rolled loop.
// LDS: RWf f32 [64][68] @0 (17408 B); RHf @17408. Total 34816 B.
// ---------------------------------------------------------------------------
__global__ __launch_bounds__(128) void attn_mfma_kernel(
    const bf16* __restrict__ qT, const bf16* __restrict__ kR, const bf16* __restrict__ vW,
    const float* __restrict__ krw, const float* __restrict__ krh,
    bf16* __restrict__ attL)
{
  __shared__ __align__(16) char smem[34816];
  float* RWf = (float*)smem;             // [64 m][68]
  float* RHf = (float*)(smem + 17408);   // [64 m][68]

  const float L2E = 1.4426950408889634f;

  int tid = threadIdx.x;
  int lane = tid & 63, wave = tid >> 6;      // wave in {0,1}
  int m16 = lane & 15, quad = lane >> 4;
  int bid = blockIdx.x;
  // same head -> same blockIdx mod 8 -> same XCD (round-robin heuristic)
  int head = ((bid & 7) << 3) | ((bid >> 3) & 7);
  int qt = bid >> 6;                 // 0..15, 64 q rows per block
  int row0 = qt * 64;
  int b = head >> 3, h = head & 7;

  // ---- rel-logit tables via MFMA (wave w: m-tiles 2w, 2w+1) ----
#pragma unroll
  for (int mt = 0; mt < 2; ++mt) {
    int mtile = wave * 2 + mt;
    int mrow = mtile * 16 + m16;
    bool valid = (mrow < 63);
    float4 w0 = make_float4(0.f, 0.f, 0.f, 0.f), w1 = w0, h0 = w0, h1 = w0;
    if (valid) {
      w0 = *(const float4*)(krw + mrow * 32 + quad * 8);
      w1 = *(const float4*)(krw + mrow * 32 + quad * 8 + 4);
      h0 = *(const float4*)(krh + mrow * 32 + quad * 8);
      h1 = *(const float4*)(krh + mrow * 32 + quad * 8 + 4);
    }
    union { unsigned int w[4]; bf16x8 v; } aw, ah;
    aw.w[0] = cvt_pk_bf16(w0.x * L2E, w0.y * L2E);
    aw.w[1] = cvt_pk_bf16(w0.z * L2E, w0.w * L2E);
    aw.w[2] = cvt_pk_bf16(w1.x * L2E, w1.y * L2E);
    aw.w[3] = cvt_pk_bf16(w1.z * L2E, w1.w * L2E);
    ah.w[0] = cvt_pk_bf16(h0.x * L2E, h0.y * L2E);
    ah.w[1] = cvt_pk_bf16(h0.z * L2E, h0.w * L2E);
    ah.w[2] = cvt_pk_bf16(h1.x * L2E, h1.y * L2E);
    ah.w[3] = cvt_pk_bf16(h1.z * L2E, h1.w * L2E);
#pragma unroll
    for (int nt = 0; nt < 4; ++nt) {
      bf16x8 qf = *(const bf16x8*)(
          qT + ((size_t)head * 1024 + row0 + nt * 16 + m16) * 32 + quad * 8);
      f32x4 z = (f32x4){0.f, 0.f, 0.f, 0.f};
      f32x4 dw = __builtin_amdgcn_mfma_f32_16x16x32_bf16(aw.v, qf, z, 0, 0, 0);
      f32x4 dh = __builtin_amdgcn_mfma_f32_16x16x32_bf16(ah.v, qf, z, 0, 0, 0);
#pragma unroll
      for (int i = 0; i < 4; ++i) {
        int mr = mtile * 16 + quad * 4 + i;     // D row = m (rel index)
        RWf[mr * 68 + nt * 16 + m16] = dw[i];
        RHf[mr * 68 + nt * 16 + m16] = dh[i];
      }
    }
  }
  __syncthreads();   // tables complete; read-only from here; NO more barriers

  // ---- Q fragments (B-operand) + chunk-invariant RW registers, per subtile
  bf16x8 afrag[2];
  float rwreg[2][2][4];
  int qloc0 = wave * 32 + m16;       // sub 0; sub 1 adds 16
#pragma unroll
  for (int sub = 0; sub < 2; ++sub) {
    int qloc = qloc0 + sub * 16;
    afrag[sub] = *(const bf16x8*)(
        qT + ((size_t)head * 1024 + row0 + qloc) * 32 + quad * 8);
    int qm = qloc & 31;
#pragma unroll
    for (int par = 0; par < 2; ++par)
#pragma unroll
      for (int i = 0; i < 4; ++i)
        rwreg[sub][par][i] = RWf[(par * 16 + quad * 4 + i - qm + 31) * 68 + qloc];
  }
  int qy = qt * 2 + wave;            // (qloc>>5) == wave for both subtiles
  const float* rhp0 = RHf + (31 - qy) * 68 + qloc0;        // +c*2*68 per chunk
  const float* rhp1 = rhp0 + 16;                           // sub 1 column

  // per-lane global fragment pointers (wave-independent: subs share fetches)
  const bf16* kp = kR + (size_t)head * 32768 + m16 * 32 + quad * 8;   // +c*2048 +t*512
  const bf16* vp = vW + (size_t)head * 32768 + lane * 8;              // +c*2048 +(dt*2+ks)*512

  f32x4 oacc[2][2];
#pragma unroll
  for (int sub = 0; sub < 2; ++sub) {
    oacc[sub][0] = (f32x4){0.f, 0.f, 0.f, 0.f};
    oacc[sub][1] = (f32x4){0.f, 0.f, 0.f, 0.f};
  }
  float rsp[2] = {0.f, 0.f};

#pragma unroll 1
  for (int c = 0; c < 16; ++c) {
    // issue all 8 shared fragment loads up front (latency overlaps exp below)
    union { uint4 u; bf16x8 v; } kf[4], vf[4];
#pragma unroll
    for (int t = 0; t < 4; ++t)
      kf[t].u = *(const uint4*)(kp + c * 2048 + t * 512);
#pragma unroll
    for (int q = 0; q < 4; ++q)         // q = dt*2 + ks
      vf[q].u = *(const uint4*)(vp + c * 2048 + q * 512);

    // RH for this chunk (per sub column; rows uniform per wave)
    float rh[2][2];
    rh[0][0] = rhp0[(c * 2 + 0) * 68];  rh[0][1] = rhp0[(c * 2 + 1) * 68];
    rh[1][0] = rhp1[(c * 2 + 0) * 68];  rh[1][1] = rhp1[(c * 2 + 1) * 68];

    // QK^T swapped: A = K frag (rows=keys), B = Qfrag[sub] (cols=q)
    f32x4 sacc[2][4];
#pragma unroll
    for (int t = 0; t < 4; ++t) {
      f32x4 z = (f32x4){0.f, 0.f, 0.f, 0.f};
#pragma unroll
      for (int sub = 0; sub < 2; ++sub)
        sacc[sub][t] = __builtin_amdgcn_mfma_f32_16x16x32_bf16(kf[t].v, afrag[sub], z, 0, 0, 0);
    }

    // softmax numerators in-register (lane q = qloc, key = t*16+quad*4+i)
    unsigned int pk[2][4][2];
#pragma unroll
    for (int sub = 0; sub < 2; ++sub) {
#pragma unroll
      for (int t = 0; t < 4; ++t) {
        float rhv = rh[sub][t >> 1];
        float e0 = exp2_f(fmaf(sacc[sub][t][0], L2E, rwreg[sub][t & 1][0] + rhv));
        float e1 = exp2_f(fmaf(sacc[sub][t][1], L2E, rwreg[sub][t & 1][1] + rhv));
        float e2 = exp2_f(fmaf(sacc[sub][t][2], L2E, rwreg[sub][t & 1][2] + rhv));
        float e3 = exp2_f(fmaf(sacc[sub][t][3], L2E, rwreg[sub][t & 1][3] + rhv));
        rsp[sub] += (e0 + e1) + (e2 + e3);
        pk[sub][t][0] = cvt_pk_bf16(e0, e1);
        pk[sub][t][1] = cvt_pk_bf16(e2, e3);
      }
    }

    // PV: O^T = mfma(Vfrag, P^T). kappa = ks*32 + (j>>2)*16 + quad*4 + (j&3).
#pragma unroll
    for (int ks = 0; ks < 2; ++ks) {
#pragma unroll
      for (int sub = 0; sub < 2; ++sub) {
        union { unsigned int w[4]; bf16x8 v; } pf;
        pf.w[0] = pk[sub][2 * ks][0];     pf.w[1] = pk[sub][2 * ks][1];
        pf.w[2] = pk[sub][2 * ks + 1][0]; pf.w[3] = pk[sub][2 * ks + 1][1];
#pragma unroll
        for (int dt = 0; dt < 2; ++dt) {
          oacc[sub][dt] = __builtin_amdgcn_mfma_f32_16x16x32_bf16(
              vf[dt * 2 + ks].v, pf.v, oacc[sub][dt], 0, 0, 0);
        }
      }
    }
  }

  // ---- epilogue: reduce row-sums across quads, normalize, store ----
#pragma unroll
  for (int sub = 0; sub < 2; ++sub) {
    rsp[sub] += __shfl_xor(rsp[sub], 16, 64);
    rsp[sub] += __shfl_xor(rsp[sub], 32, 64);
    float invs = 1.0f / rsp[sub];
    int grow = row0 + qloc0 + sub * 16;
#pragma unroll
    for (int dt = 0; dt < 2; ++dt) {
      uint2 st;
      st.x = cvt_pk_bf16(oacc[sub][dt][0] * invs, oacc[sub][dt][1] * invs);
      st.y = cvt_pk_bf16(oacc[sub][dt][2] * invs, oacc[sub][dt][3] * invs);
      *(uint2*)(attL + ((size_t)b * 1024 + grow) * 256 + h * 32 + dt * 16 + quad * 4) = st;
    }
  }
}

// ---------------------------------------------------------------------------
// K4: attnout 1x1 conv as MFMA GEMM 256 x 1024 x 256 per batch. (R6 version)
// Runs last; overwrites the d_out ch256+ regions that hosted wo_bf/wqb.
// ---------------------------------------------------------------------------
__global__ __launch_bounds__(256) void attnout_mfma_kernel(
    const bf16* __restrict__ attL, const float* __restrict__ w, const float* __restrict__ bias,
    float* __restrict__ out)
{
  __shared__ __align__(16) short smem[13824];
  short* aS = smem;            // [64 co][72]
  short* bS = smem + 4608;     // [128 l][72]

  int tid = threadIdx.x, lane = tid & 63, wave = tid >> 6;
  int m16 = lane & 15, quad = lane >> 4;
  int l0 = blockIdx.x * 128;
  int cotile = blockIdx.y;
  int b = blockIdx.z;
  int cbase = cotile * 64;

  f32x4 acc[8];
#pragma unroll
  for (int t = 0; t < 8; ++t) acc[t] = (f32x4){0.f, 0.f, 0.f, 0.f};

  for (int ck = 0; ck < 4; ++ck) {
    __syncthreads();
#pragma unroll
    for (int r = 0; r < 4; ++r) {
      int u = r * 256 + tid;
      int c = u >> 4, s4 = u & 15;
      float4 v = *(const float4*)(w + (size_t)(cbase + c) * 256 + ck * 64 + s4 * 4);
      unsigned int p0 = (unsigned int)f2bfbits(v.x) | ((unsigned int)f2bfbits(v.y) << 16);
      unsigned int p1 = (unsigned int)f2bfbits(v.z) | ((unsigned int)f2bfbits(v.w) << 16);
      uint2 u2; u2.x = p0; u2.y = p1;
      *(uint2*)(aS + c * 72 + s4 * 4) = u2;
    }
#pragma unroll
    for (int r = 0; r < 4; ++r) {
      int u = r * 256 + tid;
      int l = u >> 3, seg = u & 7;
      *(uint4*)(bS + l * 72 + seg * 8) =
          *(const uint4*)(attL + ((size_t)(b * 1024) + l0 + l) * 256 + ck * 64 + seg * 8);
    }
    __syncthreads();
#pragma unroll
    for (int ks = 0; ks < 2; ++ks) {
      bf16x8 af = *(const bf16x8*)(aS + (wave * 16 + m16) * 72 + ks * 32 + quad * 8);
#pragma unroll
      for (int t = 0; t < 8; ++t) {
        bf16x8 bf = *(const bf16x8*)(bS + (t * 16 + m16) * 72 + ks * 32 + quad * 8);
        acc[t] = __builtin_amdgcn_mfma_f32_16x16x32_bf16(af, bf, acc[t], 0, 0, 0);
      }
    }
  }

  int co = cbase + wave * 16 + quad * 4;
#pragma unroll
  for (int i = 0; i < 4; ++i) {
    float bv = bias[co + i];
    size_t obase = ((size_t)(b * 512) + 256 + co + i) * 1024 + l0;
#pragma unroll
    for (int t = 0; t < 8; ++t)
      out[obase + t * 16 + m16] = acc[t][i] + bv;
  }
}

// ---------------------------------------------------------------------------
extern "C" void kernel_launch(void* const* d_in, const int* in_sizes, int n_in,
                              void* d_out, int out_size, void* d_ws, size_t ws_size,
                              hipStream_t stream) {
  const float* x      = (const float*)d_in[0];
  const float* w_qkv  = (const float*)d_in[1];
  const float* b_qkv  = (const float*)d_in[2];
  const float* w_attn = (const float*)d_in[3];
  const float* b_attn = (const float*)d_in[4];
  const float* w_out  = (const float*)d_in[5];
  const float* b_out  = (const float*)d_in[6];
  const float* krw    = (const float*)d_in[7];
  const float* krh    = (const float*)d_in[8];
  float* out = (float*)d_out;

  bf16* ws    = (bf16*)d_ws;
  bf16* xT    = ws;                 // [0, 2,097,152)  read by fused conv3+qkv
  bf16* attL  = ws;                 // alias of xT     (attn -> attnout, after fused)
  bf16* qT    = ws + 2097152;       // [2,097,152, 4,194,304)
  bf16* kR    = ws + 4194304;       // [4,194,304, 6,291,456)
  bf16* vF    = ws + 6291456;       // [6,291,456, 8,388,608)  fragment-ordered V

  // wo_bf + wqb in d_out's attention halves (dead until attnout overwrites)
  bf16* wob0 = (bf16*)(out + (size_t)(0 * 512 + 256) * 1024);
  bf16* wob1 = (bf16*)(out + (size_t)(1 * 512 + 256) * 1024);
  bf16* wqb  = (bf16*)(out + (size_t)(2 * 512 + 256) * 1024);  // 384 KB of 1 MB

  prep_kernel<<<dim3(2108), 256, 0, stream>>>(x, w_out, w_qkv, xT, wob0, wob1, wqb);
  convqkv_kernel<<<dim3(1024), 256, 0, stream>>>(xT, wob0, wob1, b_out, out,
                                                 wqb, b_qkv, qT, kR, vF);
  attn_mfma_kernel<<<dim3(1024), 128, 0, stream>>>(qT, kR, vF, krw, krh, attL);
  attnout_mfma_kernel<<<dim3(8, 4, 8), 256, 0, stream>>>(attL, w_attn, b_attn, out);
}